// Round 25
// baseline (166.156 us; speedup 1.0000x reference)
//
#include <hip/hip_runtime.h>
#include <hip/hip_bf16.h>
#include <stdint.h>

using u16 = unsigned short;
using u32t = unsigned int;
typedef __bf16 bf16x8 __attribute__((ext_vector_type(8)));
typedef float f32x4 __attribute__((ext_vector_type(4)));
typedef float f32x16 __attribute__((ext_vector_type(16)));

#define SEQ_T 2048
#define DM 1024
#define NH 16
#define HD 64
#define NB 4

__device__ inline u16 f2bfu(float f) {
    __hip_bfloat16 h = __float2bfloat16(f);
    return __builtin_bit_cast(u16, h);
}

__device__ inline bf16x8 ld_frag(const u16* p) {
    return __builtin_bit_cast(bf16x8, *reinterpret_cast<const uint4*>(p));
}

__device__ inline void gload_lds16(const u16* g, u16* l) {
    __builtin_amdgcn_global_load_lds(
        (const __attribute__((address_space(1))) void*)g,
        (__attribute__((address_space(3))) void*)l, 16, 0, 0);
}

__device__ inline float fexp2(float x) { return __builtin_amdgcn_exp2f(x); }

// ---------------- fused prep: cvt_x + trans_w(Wqkv) + trans_w(Wproj) --------------
// grid 5120 x 256 thr: [0,4096) cvt_x; [4096,4864) Wqkv trans; [4864,5120) Wproj.
__global__ __launch_bounds__(256) void prep_kernel(const float* __restrict__ x,
                                                   u16* __restrict__ xb,
                                                   const float* __restrict__ Wqkv,
                                                   u16* __restrict__ wtq,
                                                   const float* __restrict__ Wproj,
                                                   u16* __restrict__ wtp) {
    __shared__ __align__(16) float tile[64][72];
    const int bid = blockIdx.x;
    const int tid = threadIdx.x;
    if (bid < 4096) {
        size_t i = (size_t)bid * 256 + tid;
        const float4* xv = reinterpret_cast<const float4*>(x);
        float4 a = xv[2 * i];
        float4 b = xv[2 * i + 1];
        u16 r[8] = {f2bfu(a.x), f2bfu(a.y), f2bfu(a.z), f2bfu(a.w),
                    f2bfu(b.x), f2bfu(b.y), f2bfu(b.z), f2bfu(b.w)};
        *reinterpret_cast<uint4*>(xb + i * 8) = *reinterpret_cast<const uint4*>(r);
        return;
    }
    const float* W;
    u16* Wt;
    int N, t;
    if (bid < 4864) {
        W = Wqkv; Wt = wtq; N = 3072; t = bid - 4096;   // 48 x 16 blocks
    } else {
        W = Wproj; Wt = wtp; N = 1024; t = bid - 4864;  // 16 x 16 blocks
    }
    const int nbx = N >> 6;
    const int n0 = (t % nbx) * 64, k0 = (t / nbx) * 64;
    const int K = 1024;
#pragma unroll
    for (int p = 0; p < 4; ++p) {
        int idx = p * 256 + tid;
        int r = idx >> 4, c = (idx & 15) * 4;
        float4 v = *reinterpret_cast<const float4*>(&W[(size_t)(k0 + r) * N + n0 + c]);
        *reinterpret_cast<float4*>(&tile[r][c]) = v;
    }
    __syncthreads();
#pragma unroll
    for (int p = 0; p < 4; ++p) {
        int idx = p * 256 + tid;
        int nr = idx >> 4, kg = (idx & 15) * 4;
        u16 u[4];
#pragma unroll
        for (int j = 0; j < 4; ++j) u[j] = f2bfu(tile[kg + j][nr]);
        *reinterpret_cast<uint2*>(&Wt[(size_t)(n0 + nr) * K + k0 + kg]) =
            *reinterpret_cast<const uint2*>(u);
    }
}

// ---------------- GEMM A: 256x128 tile, BK=32, ring-3 (for the big gemm1) -------
template <int F32OUT, int SCALEQ>
__global__ __launch_bounds__(512, 2) void gemm_r3(const u16* __restrict__ A,
                                                  const u16* __restrict__ Bt,
                                                  const float* __restrict__ bias,
                                                  float* __restrict__ Cf,
                                                  u16* __restrict__ Cb,
                                                  int M, int N, int K) {
    __shared__ __align__(16) u16 smem[36864];  // 3 x (A 8192 + B 4096) u16 = 72KB
    const int tid = threadIdx.x;
    const int wid = tid >> 6, lane = tid & 63;
    const int llo = lane & 15, lhi = lane >> 4;
    const int wm = wid >> 1, wn = wid & 1;
    const int cpx = gridDim.x >> 3;
    const int swz = (blockIdx.x & 7) * cpx + (blockIdx.x >> 3);
    const int nb = N >> 7;
    const int m0 = (swz / nb) << 8, n0 = (swz % nb) << 7;
    const int T = K >> 5;

    f32x4 acc[4][4];
#pragma unroll
    for (int i = 0; i < 4; ++i)
#pragma unroll
        for (int j = 0; j < 4; ++j) acc[i][j] = (f32x4){0.f, 0.f, 0.f, 0.f};

    auto stage = [&](int t, int sb) {
        const int kb = t << 5;
#pragma unroll
        for (int j = 0; j < 2; ++j) {
            int c = j * 512 + tid;
            int row = c >> 2, kc = (c & 3) * 8;
            gload_lds16(A + (size_t)(m0 + row) * K + kb + kc, smem + sb + c * 8);
        }
        {
            int c = tid;
            int row = c >> 2, kc = (c & 3) * 8;
            gload_lds16(Bt + (size_t)(n0 + row) * K + kb + kc,
                        smem + sb + 8192 + c * 8);
        }
    };

    stage(0, 0);
    stage(1, 12288);

    for (int t = 0; t < T; ++t) {
        if (t == T - 1)
            asm volatile("s_waitcnt vmcnt(0)" ::: "memory");
        else
            asm volatile("s_waitcnt vmcnt(3)" ::: "memory");
        __builtin_amdgcn_sched_barrier(0);
        __builtin_amdgcn_s_barrier();
        __builtin_amdgcn_sched_barrier(0);
        const u16* Ab = smem + (t % 3) * 12288;
        const u16* Bb = Ab + 8192;
        bf16x8 af[4], bfr[4];
#pragma unroll
        for (int mf = 0; mf < 4; ++mf)
            af[mf] = ld_frag(Ab + (wm * 64 + mf * 16 + llo) * 32 + lhi * 8);
#pragma unroll
        for (int nf = 0; nf < 4; ++nf)
            bfr[nf] = ld_frag(Bb + (wn * 64 + nf * 16 + llo) * 32 + lhi * 8);
        if (t + 2 < T) stage(t + 2, ((t + 2) % 3) * 12288);
        __builtin_amdgcn_s_setprio(1);
#pragma unroll
        for (int mf = 0; mf < 4; ++mf)
#pragma unroll
            for (int nf = 0; nf < 4; ++nf)
                acc[mf][nf] = __builtin_amdgcn_mfma_f32_16x16x32_bf16(
                    af[mf], bfr[nf], acc[mf][nf], 0, 0, 0);
        __builtin_amdgcn_s_setprio(0);
    }

    const float SC2 = 0.18033688f;  // 0.125 * log2(e)
    const int row_base = m0 + wm * 64;
    const int col_base = n0 + wn * 64;
#pragma unroll
    for (int nf = 0; nf < 4; ++nf) {
        int col = col_base + nf * 16 + llo;
        float bv = bias[col];
        const bool doScale = SCALEQ && (col < 1024);
#pragma unroll
        for (int mf = 0; mf < 4; ++mf) {
#pragma unroll
            for (int r = 0; r < 4; ++r) {
                int row = row_base + mf * 16 + lhi * 4 + r;
                float v = acc[mf][nf][r] + bv;
                if (doScale) v *= SC2;
                if (F32OUT)
                    Cf[(size_t)row * N + col] = v;
                else
                    Cb[(size_t)row * N + col] = f2bfu(v);
            }
        }
    }
}

// ---------------- GEMM B: 128x128 tile, BK=32, ring-3 (for the small gemm2) ------
template <int F32OUT, int SCALEQ>
__global__ __launch_bounds__(256, 3) void gemm_r4(const u16* __restrict__ A,
                                                  const u16* __restrict__ Bt,
                                                  const float* __restrict__ bias,
                                                  float* __restrict__ Cf,
                                                  u16* __restrict__ Cb,
                                                  int M, int N, int K) {
    __shared__ __align__(16) u16 smem[24576];  // 3 x (A 4096 + B 4096) u16 = 48KB
    const int tid = threadIdx.x;
    const int wid = tid >> 6, lane = tid & 63;
    const int llo = lane & 15, lhi = lane >> 4;
    const int wm = wid >> 1, wn = wid & 1;
    const int cpx = gridDim.x >> 3;
    const int swz = (blockIdx.x & 7) * cpx + (blockIdx.x >> 3);
    const int nb = N >> 7;
    const int m0 = (swz / nb) << 7, n0 = (swz % nb) << 7;
    const int T = K >> 5;

    f32x4 acc[4][4];
#pragma unroll
    for (int i = 0; i < 4; ++i)
#pragma unroll
        for (int j = 0; j < 4; ++j) acc[i][j] = (f32x4){0.f, 0.f, 0.f, 0.f};

    auto stage = [&](int t, int sb) {
        const int kb = t << 5;
#pragma unroll
        for (int j = 0; j < 2; ++j) {
            int c = j * 256 + tid;
            int row = c >> 2, kc = (c & 3) * 8;
            gload_lds16(A + (size_t)(m0 + row) * K + kb + kc, smem + sb + c * 8);
        }
#pragma unroll
        for (int j = 0; j < 2; ++j) {
            int c = j * 256 + tid;
            int row = c >> 2, kc = (c & 3) * 8;
            gload_lds16(Bt + (size_t)(n0 + row) * K + kb + kc,
                        smem + sb + 4096 + c * 8);
        }
    };

    stage(0, 0);
    stage(1, 8192);

    for (int t = 0; t < T; ++t) {
        if (t == T - 1)
            asm volatile("s_waitcnt vmcnt(0)" ::: "memory");
        else
            asm volatile("s_waitcnt vmcnt(4)" ::: "memory");
        __builtin_amdgcn_sched_barrier(0);
        __builtin_amdgcn_s_barrier();
        __builtin_amdgcn_sched_barrier(0);
        const u16* Ab = smem + (t % 3) * 8192;
        const u16* Bb = Ab + 4096;
        bf16x8 af[4], bfr[4];
#pragma unroll
        for (int mf = 0; mf < 4; ++mf)
            af[mf] = ld_frag(Ab + (wm * 64 + mf * 16 + llo) * 32 + lhi * 8);
#pragma unroll
        for (int nf = 0; nf < 4; ++nf)
            bfr[nf] = ld_frag(Bb + (wn * 64 + nf * 16 + llo) * 32 + lhi * 8);
        if (t + 2 < T) stage(t + 2, ((t + 2) % 3) * 8192);
        __builtin_amdgcn_s_setprio(1);
#pragma unroll
        for (int mf = 0; mf < 4; ++mf)
#pragma unroll
            for (int nf = 0; nf < 4; ++nf)
                acc[mf][nf] = __builtin_amdgcn_mfma_f32_16x16x32_bf16(
                    af[mf], bfr[nf], acc[mf][nf], 0, 0, 0);
        __builtin_amdgcn_s_setprio(0);
    }

    const float SC2 = 0.18033688f;  // 0.125 * log2(e)
    const int row_base = m0 + wm * 64;
    const int col_base = n0 + wn * 64;
#pragma unroll
    for (int nf = 0; nf < 4; ++nf) {
        int col = col_base + nf * 16 + llo;
        float bv = bias[col];
        const bool doScale = SCALEQ && (col < 1024);
#pragma unroll
        for (int mf = 0; mf < 4; ++mf) {
#pragma unroll
            for (int r = 0; r < 4; ++r) {
                int row = row_base + mf * 16 + lhi * 4 + r;
                float v = acc[mf][nf][r] + bv;
                if (doScale) v *= SC2;
                if (F32OUT)
                    Cf[(size_t)row * N + col] = v;
                else
                    Cb[(size_t)row * N + col] = f2bfu(v);
            }
        }
    }
}

// ---------------- causal flash attention: interleaved substeps ----------
// Per 128-kv tile: QK_A; QK_B; SM_A; PV_A; SM_B; PV_B -- QK_B's MFMAs fly under
// SM_A's VALU; SM_B's exp/sum overlaps PV_A (defer-max skips the oac rescale
// on most tiles, so no oac dependency). Sync identical to round-22 winner.
__global__ __launch_bounds__(512, 2) void attn_kernel(const u16* __restrict__ qkv,
                                                      u16* __restrict__ o) {
    __shared__ __align__(16) u16 smem[34048];  // K:2x8320 @0, Vt:2x8704 @16640
    const int bid = blockIdx.x;
    const int amap[8] = {7, 5, 3, 1, 6, 4, 2, 0};  // f(g+4) = f(g)-1
    const int bh = bid & 63;
    const int qc = amap[bid >> 6];
    const int b = bh >> 4, h = bh & 15;
    const int tid = threadIdx.x;
    const int wid = tid >> 6, lane = tid & 63;
    const int l31 = lane & 31, lh = lane >> 5;
    const u16* base = qkv + (size_t)b * SEQ_T * (3 * DM);
    const int qrow0 = qc * 256 + wid * 32;
    const int q_abs = qrow0 + l31;
    const int nkv2 = 2 * qc + 2;

    bf16x8 qf[4];
    {
        const u16* qp = base + (size_t)q_abs * (3 * DM) + h * HD + lh * 8;
#pragma unroll
        for (int km = 0; km < 4; ++km) qf[km] = ld_frag(qp + km * 16);
    }

    f32x16 oac0, oac1;
#pragma unroll
    for (int r = 0; r < 16; ++r) { oac0[r] = 0.f; oac1[r] = 0.f; }
    float m_run = -1e30f, l_run = 0.f;

    uint4 va, vb;
    const int vpr = tid >> 3, vm = tid & 7;

    auto stageK = [&](int kb2, int bi2) {
#pragma unroll
        for (int p = 0; p < 2; ++p) {
            int kv = p * 64 + wid * 8 + (lane >> 3);
            int cl = lane & 7;
            const u16* src = base + (size_t)(kb2 * 128 + kv) * (3 * DM) + DM + h * HD +
                             ((cl ^ (kv & 7)) * 8);
            gload_lds16(src, smem + bi2 * 8320 + (p * 8 + wid) * 520);
        }
    };
    auto loadV = [&](int kb2) {
        const u16* vp =
            base + (size_t)(kb2 * 128 + 2 * vpr) * (3 * DM) + 2 * DM + h * HD + vm * 8;
        va = *reinterpret_cast<const uint4*>(vp);
        vb = *reinterpret_cast<const uint4*>(vp + 3 * DM);
    };
    auto writeV = [&](int bi2) {
        u16 ua[8], ub[8];
        *reinterpret_cast<uint4*>(ua) = va;
        *reinterpret_cast<uint4*>(ub) = vb;
        const int cbk = vpr >> 2, off = 2 * (vpr & 3);
        const int sw = (2 * vm) & 7;
        u16* vt = smem + 16640 + bi2 * 8704;
#pragma unroll
        for (int j = 0; j < 8; ++j) {
            int d = vm * 8 + j;
            u32t val = (u32t)ua[j] | ((u32t)ub[j] << 16);
            *reinterpret_cast<u32t*>(vt + d * 136 + ((cbk ^ sw) * 8) + off) = val;
        }
    };

    loadV(0);
    stageK(0, 0);
    writeV(0);
    asm volatile("s_waitcnt lgkmcnt(0)" ::: "memory");
    asm volatile("s_waitcnt vmcnt(1)" ::: "memory");
    __builtin_amdgcn_sched_barrier(0);
    __builtin_amdgcn_s_barrier();
    __builtin_amdgcn_sched_barrier(0);

    const int vsw = (2 * (l31 >> 3)) & 7;
    const int qmax = qrow0 + 31;
    const int krow0 = (l31 >> 3) * 520 + (l31 & 7) * 64;
    const int krow1 = (4 + (l31 >> 3)) * 520 + (l31 & 7) * 64;

    for (int kb2 = 0; kb2 < nkv2; ++kb2) {
        const int cur = kb2 & 1;
        const bool pre = (kb2 + 1 < nkv2);
        if (pre) { loadV(kb2 + 1); stageK(kb2 + 1, cur ^ 1); }

        const int kv0A = kb2 * 128, kv0B = kv0A + 64;
        const bool runA = (kv0A <= qmax), runB = (kv0B <= qmax);
        f32x16 sA0, sA1, sB0, sB1;

        // ---- QK for substep A ----
        if (runA) {
#pragma unroll
            for (int r = 0; r < 16; ++r) { sA0[r] = 0.f; sA1[r] = 0.f; }
            const u16* kbase = smem + cur * 8320;
#pragma unroll
            for (int km = 0; km < 4; ++km) {
                bf16x8 kf = ld_frag(kbase + krow0 + (((km * 2 + lh) ^ (l31 & 7)) * 8));
                sA0 = __builtin_amdgcn_mfma_f32_32x32x16_bf16(kf, qf[km], sA0, 0, 0, 0);
            }
#pragma unroll
            for (int km = 0; km < 4; ++km) {
                bf16x8 kf = ld_frag(kbase + krow1 + (((km * 2 + lh) ^ (l31 & 7)) * 8));
                sA1 = __builtin_amdgcn_mfma_f32_32x32x16_bf16(kf, qf[km], sA1, 0, 0, 0);
            }
            if (kv0A + 63 > qrow0) {
#pragma unroll
                for (int r = 0; r < 16; ++r) {
                    int ka = kv0A + (r & 3) + 8 * (r >> 2) + 4 * lh;
                    if (ka > q_abs) sA0[r] = -1e30f;
                    if (ka + 32 > q_abs) sA1[r] = -1e30f;
                }
            }
        }

        // ---- wait K half-1, then QK for substep B (flies under SM_A) ----
        if (pre) asm volatile("s_waitcnt vmcnt(4)" ::: "memory");
        else     asm volatile("s_waitcnt vmcnt(0)" ::: "memory");
        __builtin_amdgcn_sched_barrier(0);
        if (runB) {
#pragma unroll
            for (int r = 0; r < 16; ++r) { sB0[r] = 0.f; sB1[r] = 0.f; }
            const u16* kbase = smem + cur * 8320 + 4160;
#pragma unroll
            for (int km = 0; km < 4; ++km) {
                bf16x8 kf = ld_frag(kbase + krow0 + (((km * 2 + lh) ^ (l31 & 7)) * 8));
                sB0 = __builtin_amdgcn_mfma_f32_32x32x16_bf16(kf, qf[km], sB0, 0, 0, 0);
            }
#pragma unroll
            for (int km = 0; km < 4; ++km) {
                bf16x8 kf = ld_frag(kbase + krow1 + (((km * 2 + lh) ^ (l31 & 7)) * 8));
                sB1 = __builtin_amdgcn_mfma_f32_32x32x16_bf16(kf, qf[km], sB1, 0, 0, 0);
            }
            if (kv0B + 63 > qrow0) {
#pragma unroll
                for (int r = 0; r < 16; ++r) {
                    int ka = kv0B + (r & 3) + 8 * (r >> 2) + 4 * lh;
                    if (ka > q_abs) sB0[r] = -1e30f;
                    if (ka + 32 > q_abs) sB1[r] = -1e30f;
                }
            }
        }

        // ---- SM_A + PV_A ----
        if (runA) {
            float t16[16];
#pragma unroll
            for (int r = 0; r < 16; ++r) t16[r] = fmaxf(sA0[r], sA1[r]);
#pragma unroll
            for (int r = 0; r < 8; ++r) t16[r] = fmaxf(t16[r], t16[r + 8]);
#pragma unroll
            for (int r = 0; r < 4; ++r) t16[r] = fmaxf(t16[r], t16[r + 4]);
            float pm = fmaxf(fmaxf(t16[0], t16[1]), fmaxf(t16[2], t16[3]));
            pm = fmaxf(pm, __shfl_xor(pm, 32));
            if (!__all(pm - m_run <= 8.f)) {
                const float mnew = fmaxf(m_run, pm);
                const float sc = fexp2(m_run - mnew);
                m_run = mnew;
                l_run *= sc;
#pragma unroll
                for (int r = 0; r < 16; ++r) { oac0[r] *= sc; oac1[r] *= sc; }
            }
            float a16[16];
#pragma unroll
            for (int r = 0; r < 16; ++r) { sA0[r] = fexp2(sA0[r] - m_run); }
#pragma unroll
            for (int r = 0; r < 16; ++r) { sA1[r] = fexp2(sA1[r] - m_run); }
#pragma unroll
            for (int r = 0; r < 16; ++r) a16[r] = sA0[r] + sA1[r];
#pragma unroll
            for (int r = 0; r < 8; ++r) a16[r] += a16[r + 8];
#pragma unroll
            for (int r = 0; r < 4; ++r) a16[r] += a16[r + 4];
            float sum = (a16[0] + a16[1]) + (a16[2] + a16[3]);
            sum += __shfl_xor(sum, 32);
            l_run += sum;

            u32t pk0[8], pk1[8];
#pragma unroll
            for (int w = 0; w < 8; ++w) {
                float a0 = sA0[2 * w], b0 = sA0[2 * w + 1];
                float a1 = sA1[2 * w], b1 = sA1[2 * w + 1];
                asm("v_cvt_pk_bf16_f32 %0, %1, %2" : "=v"(pk0[w]) : "v"(a0), "v"(b0));
                asm("v_cvt_pk_bf16_f32 %0, %1, %2" : "=v"(pk1[w]) : "v"(a1), "v"(b1));
            }
            asm("v_permlane32_swap_b32 %0, %1" : "+v"(pk0[0]), "+v"(pk0[2]));
            asm("v_permlane32_swap_b32 %0, %1" : "+v"(pk0[1]), "+v"(pk0[3]));
            asm("v_permlane32_swap_b32 %0, %1" : "+v"(pk0[4]), "+v"(pk0[6]));
            asm("v_permlane32_swap_b32 %0, %1" : "+v"(pk0[5]), "+v"(pk0[7]));
            asm("v_permlane32_swap_b32 %0, %1" : "+v"(pk1[0]), "+v"(pk1[2]));
            asm("v_permlane32_swap_b32 %0, %1" : "+v"(pk1[1]), "+v"(pk1[3]));
            asm("v_permlane32_swap_b32 %0, %1" : "+v"(pk1[4]), "+v"(pk1[6]));
            asm("v_permlane32_swap_b32 %0, %1" : "+v"(pk1[5]), "+v"(pk1[7]));
            bf16x8 pf[4];
            {
                uint4 t0 = {pk0[0], pk0[1], pk0[2], pk0[3]};
                uint4 t1 = {pk0[4], pk0[5], pk0[6], pk0[7]};
                uint4 t2 = {pk1[0], pk1[1], pk1[2], pk1[3]};
                uint4 t3 = {pk1[4], pk1[5], pk1[6], pk1[7]};
                pf[0] = __builtin_bit_cast(bf16x8, t0);
                pf[1] = __builtin_bit_cast(bf16x8, t1);
                pf[2] = __builtin_bit_cast(bf16x8, t2);
                pf[3] = __builtin_bit_cast(bf16x8, t3);
            }
            const u16* vbase = smem + 16640 + cur * 8704;
#pragma unroll
            for (int km = 0; km < 4; ++km) {
                bf16x8 vf = ld_frag(vbase + l31 * 136 + (((km * 2 + lh) ^ vsw) * 8));
                oac0 = __builtin_amdgcn_mfma_f32_32x32x16_bf16(vf, pf[km], oac0, 0, 0, 0);
            }
#pragma unroll
            for (int km = 0; km < 4; ++km) {
                bf16x8 vf = ld_frag(vbase + (32 + l31) * 136 + (((km * 2 + lh) ^ vsw) * 8));
                oac1 = __builtin_amdgcn_mfma_f32_32x32x16_bf16(vf, pf[km], oac1, 0, 0, 0);
            }
        }

        // ---- SM_B + PV_B (exp/sum overlaps PV_A's MFMAs) ----
        if (runB) {
            float t16[16];
#pragma unroll
            for (int r = 0; r < 16; ++r) t16[r] = fmaxf(sB0[r], sB1[r]);
#pragma unroll
            for (int r = 0; r < 8; ++r) t16[r] = fmaxf(t16[r], t16[r + 8]);
#pragma unroll
            for (int r = 0; r < 4; ++r) t16[r] = fmaxf(t16[r], t16[r + 4]);
            float pm = fmaxf(fmaxf(t16[0], t16[1]), fmaxf(t16[2], t16[3]));
            pm = fmaxf(pm, __shfl_xor(pm, 32));
            if (!__all(pm - m_run <= 8.f)) {
                const float mnew = fmaxf(m_run, pm);
                const float sc = fexp2(m_run - mnew);
                m_run = mnew;
                l_run *= sc;
#pragma unroll
                for (int r = 0; r < 16; ++r) { oac0[r] *= sc; oac1[r] *= sc; }
            }
            float a16[16];
#pragma unroll
            for (int r = 0; r < 16; ++r) { sB0[r] = fexp2(sB0[r] - m_run); }
#pragma unroll
            for (int r = 0; r < 16; ++r) { sB1[r] = fexp2(sB1[r] - m_run); }
#pragma unroll
            for (int r = 0; r < 16; ++r) a16[r] = sB0[r] + sB1[r];
#pragma unroll
            for (int r = 0; r < 8; ++r) a16[r] += a16[r + 8];
#pragma unroll
            for (int r = 0; r < 4; ++r) a16[r] += a16[r + 4];
            float sum = (a16[0] + a16[1]) + (a16[2] + a16[3]);
            sum += __shfl_xor(sum, 32);
            l_run += sum;

            u32t pk0[8], pk1[8];
#pragma unroll
            for (int w = 0; w < 8; ++w) {
                float a0 = sB0[2 * w], b0 = sB0[2 * w + 1];
                float a1 = sB1[2 * w], b1 = sB1[2 * w + 1];
                asm("v_cvt_pk_bf16_f32 %0, %1, %2" : "=v"(pk0[w]) : "v"(a0), "v"(b0));
                asm("v_cvt_pk_bf16_f32 %0, %1, %2" : "=v"(pk1[w]) : "v"(a1), "v"(b1));
            }
            asm("v_permlane32_swap_b32 %0, %1" : "+v"(pk0[0]), "+v"(pk0[2]));
            asm("v_permlane32_swap_b32 %0, %1" : "+v"(pk0[1]), "+v"(pk0[3]));
            asm("v_permlane32_swap_b32 %0, %1" : "+v"(pk0[4]), "+v"(pk0[6]));
            asm("v_permlane32_swap_b32 %0, %1" : "+v"(pk0[5]), "+v"(pk0[7]));
            asm("v_permlane32_swap_b32 %0, %1" : "+v"(pk1[0]), "+v"(pk1[2]));
            asm("v_permlane32_swap_b32 %0, %1" : "+v"(pk1[1]), "+v"(pk1[3]));
            asm("v_permlane32_swap_b32 %0, %1" : "+v"(pk1[4]), "+v"(pk1[6]));
            asm("v_permlane32_swap_b32 %0, %1" : "+v"(pk1[5]), "+v"(pk1[7]));
            bf16x8 pf[4];
            {
                uint4 t0 = {pk0[0], pk0[1], pk0[2], pk0[3]};
                uint4 t1 = {pk0[4], pk0[5], pk0[6], pk0[7]};
                uint4 t2 = {pk1[0], pk1[1], pk1[2], pk1[3]};
                uint4 t3 = {pk1[4], pk1[5], pk1[6], pk1[7]};
                pf[0] = __builtin_bit_cast(bf16x8, t0);
                pf[1] = __builtin_bit_cast(bf16x8, t1);
                pf[2] = __builtin_bit_cast(bf16x8, t2);
                pf[3] = __builtin_bit_cast(bf16x8, t3);
            }
            const u16* vbase = smem + 16640 + cur * 8704;
#pragma unroll
            for (int km = 0; km < 4; ++km) {
                bf16x8 vf = ld_frag(vbase + l31 * 136 + ((8 + ((km * 2 + lh) ^ vsw)) * 8));
                oac0 = __builtin_amdgcn_mfma_f32_32x32x16_bf16(vf, pf[km], oac0, 0, 0, 0);
            }
#pragma unroll
            for (int km = 0; km < 4; ++km) {
                bf16x8 vf = ld_frag(vbase + (32 + l31) * 136 + ((8 + ((km * 2 + lh) ^ vsw)) * 8));
                oac1 = __builtin_amdgcn_mfma_f32_32x32x16_bf16(vf, pf[km], oac1, 0, 0, 0);
            }
        }

        if (pre) {
            writeV(cur ^ 1);
            asm volatile("s_waitcnt lgkmcnt(0)" ::: "memory");
            asm volatile("s_waitcnt vmcnt(1)" ::: "memory");
        } else {
            asm volatile("s_waitcnt lgkmcnt(0)" ::: "memory");
        }
        __builtin_amdgcn_sched_barrier(0);
        __builtin_amdgcn_s_barrier();
        __builtin_amdgcn_sched_barrier(0);
    }

    const float inv = 1.f / l_run;
    u16* osh = smem + wid * 2240;
#pragma unroll
    for (int r = 0; r < 16; ++r) {
        int dl = (r & 3) + 8 * (r >> 2) + 4 * lh;
        osh[l31 * 70 + dl] = f2bfu(oac0[r] * inv);
        osh[l31 * 70 + 32 + dl] = f2bfu(oac1[r] * inv);
    }
    __syncthreads();
    {
        const u16* rs = osh + l31 * 70 + lh * 32;
        u16* op = o + (size_t)(b * SEQ_T + qrow0 + l31) * DM + h * HD + lh * 32;
        u32t w[16];
#pragma unroll
        for (int i = 0; i < 16; ++i) w[i] = *reinterpret_cast<const u32t*>(rs + i * 2);
#pragma unroll
        for (int i = 0; i < 4; ++i) {
            uint4 t = {w[4 * i], w[4 * i + 1], w[4 * i + 2], w[4 * i + 3]};
            *reinterpret_cast<uint4*>(op + 8 * i) = t;
        }
    }
}

extern "C" void kernel_launch(void* const* d_in, const int* in_sizes, int n_in,
                              void* d_out, int out_size, void* d_ws, size_t ws_size,
                              hipStream_t stream) {
    const float* x = (const float*)d_in[0];
    const float* Wqkv = (const float*)d_in[1];
    const float* bqkv = (const float*)d_in[2];
    const float* Wproj = (const float*)d_in[3];
    const float* bproj = (const float*)d_in[4];
    float* out = (float*)d_out;
    char* ws = (char*)d_ws;

    u16* xb   = (u16*)(ws);                         // 16,777,216 B
    u16* wtq  = (u16*)(ws + 16777216);              //  6,291,456 B
    u16* wtp  = (u16*)(ws + 23068672);              //  2,097,152 B
    u16* qkvb = (u16*)(ws + 25165824);              // 50,331,648 B
    u16* ob   = (u16*)(ws + 75497472);              // 16,777,216 B

    prep_kernel<<<5120, 256, 0, stream>>>(x, xb, Wqkv, wtq, Wproj, wtp);

    gemm_r3<0, 1><<<768, 512, 0, stream>>>(
        xb, wtq, bqkv, nullptr, qkvb, 8192, 3072, 1024);

    attn_kernel<<<512, 512, 0, stream>>>(qkvb, ob);

    gemm_r4<1, 0><<<512, 256, 0, stream>>>(
        ob, wtp, bproj, out, nullptr, 8192, 1024, 1024);
}

// Round 26
// 160.395 us; speedup vs baseline: 1.0359x; 1.0359x over previous
//
#include <hip/hip_runtime.h>
#include <hip/hip_bf16.h>
#include <stdint.h>

using u16 = unsigned short;
using u32t = unsigned int;
typedef __bf16 bf16x8 __attribute__((ext_vector_type(8)));
typedef float f32x4 __attribute__((ext_vector_type(4)));
typedef float f32x16 __attribute__((ext_vector_type(16)));

#define SEQ_T 2048
#define DM 1024
#define NH 16
#define HD 64
#define NB 4

__device__ inline u16 f2bfu(float f) {
    __hip_bfloat16 h = __float2bfloat16(f);
    return __builtin_bit_cast(u16, h);
}

__device__ inline bf16x8 ld_frag(const u16* p) {
    return __builtin_bit_cast(bf16x8, *reinterpret_cast<const uint4*>(p));
}

__device__ inline void gload_lds16(const u16* g, u16* l) {
    __builtin_amdgcn_global_load_lds(
        (const __attribute__((address_space(1))) void*)g,
        (__attribute__((address_space(3))) void*)l, 16, 0, 0);
}

__device__ inline float fexp2(float x) { return __builtin_amdgcn_exp2f(x); }

// ---------------- fused prep: cvt_x + trans_w(Wqkv) + trans_w(Wproj) --------------
__global__ __launch_bounds__(256) void prep_kernel(const float* __restrict__ x,
                                                   u16* __restrict__ xb,
                                                   const float* __restrict__ Wqkv,
                                                   u16* __restrict__ wtq,
                                                   const float* __restrict__ Wproj,
                                                   u16* __restrict__ wtp) {
    __shared__ __align__(16) float tile[64][72];
    const int bid = blockIdx.x;
    const int tid = threadIdx.x;
    if (bid < 4096) {
        size_t i = (size_t)bid * 256 + tid;
        const float4* xv = reinterpret_cast<const float4*>(x);
        float4 a = xv[2 * i];
        float4 b = xv[2 * i + 1];
        u16 r[8] = {f2bfu(a.x), f2bfu(a.y), f2bfu(a.z), f2bfu(a.w),
                    f2bfu(b.x), f2bfu(b.y), f2bfu(b.z), f2bfu(b.w)};
        *reinterpret_cast<uint4*>(xb + i * 8) = *reinterpret_cast<const uint4*>(r);
        return;
    }
    const float* W;
    u16* Wt;
    int N, t;
    if (bid < 4864) {
        W = Wqkv; Wt = wtq; N = 3072; t = bid - 4096;
    } else {
        W = Wproj; Wt = wtp; N = 1024; t = bid - 4864;
    }
    const int nbx = N >> 6;
    const int n0 = (t % nbx) * 64, k0 = (t / nbx) * 64;
    const int K = 1024;
#pragma unroll
    for (int p = 0; p < 4; ++p) {
        int idx = p * 256 + tid;
        int r = idx >> 4, c = (idx & 15) * 4;
        float4 v = *reinterpret_cast<const float4*>(&W[(size_t)(k0 + r) * N + n0 + c]);
        *reinterpret_cast<float4*>(&tile[r][c]) = v;
    }
    __syncthreads();
#pragma unroll
    for (int p = 0; p < 4; ++p) {
        int idx = p * 256 + tid;
        int nr = idx >> 4, kg = (idx & 15) * 4;
        u16 u[4];
#pragma unroll
        for (int j = 0; j < 4; ++j) u[j] = f2bfu(tile[kg + j][nr]);
        *reinterpret_cast<uint2*>(&Wt[(size_t)(n0 + nr) * K + k0 + kg]) =
            *reinterpret_cast<const uint2*>(u);
    }
}

// ---------------- GEMM A: 256x128 tile, BK=32, ring-3 (big gemm1) -------
template <int F32OUT, int SCALEQ>
__global__ __launch_bounds__(512, 2) void gemm_r3(const u16* __restrict__ A,
                                                  const u16* __restrict__ Bt,
                                                  const float* __restrict__ bias,
                                                  float* __restrict__ Cf,
                                                  u16* __restrict__ Cb,
                                                  int M, int N, int K) {
    __shared__ __align__(16) u16 smem[36864];
    const int tid = threadIdx.x;
    const int wid = tid >> 6, lane = tid & 63;
    const int llo = lane & 15, lhi = lane >> 4;
    const int wm = wid >> 1, wn = wid & 1;
    const int cpx = gridDim.x >> 3;
    const int swz = (blockIdx.x & 7) * cpx + (blockIdx.x >> 3);
    const int nb = N >> 7;
    const int m0 = (swz / nb) << 8, n0 = (swz % nb) << 7;
    const int T = K >> 5;

    f32x4 acc[4][4];
#pragma unroll
    for (int i = 0; i < 4; ++i)
#pragma unroll
        for (int j = 0; j < 4; ++j) acc[i][j] = (f32x4){0.f, 0.f, 0.f, 0.f};

    auto stage = [&](int t, int sb) {
        const int kb = t << 5;
#pragma unroll
        for (int j = 0; j < 2; ++j) {
            int c = j * 512 + tid;
            int row = c >> 2, kc = (c & 3) * 8;
            gload_lds16(A + (size_t)(m0 + row) * K + kb + kc, smem + sb + c * 8);
        }
        {
            int c = tid;
            int row = c >> 2, kc = (c & 3) * 8;
            gload_lds16(Bt + (size_t)(n0 + row) * K + kb + kc,
                        smem + sb + 8192 + c * 8);
        }
    };

    stage(0, 0);
    stage(1, 12288);

    for (int t = 0; t < T; ++t) {
        if (t == T - 1)
            asm volatile("s_waitcnt vmcnt(0)" ::: "memory");
        else
            asm volatile("s_waitcnt vmcnt(3)" ::: "memory");
        __builtin_amdgcn_sched_barrier(0);
        __builtin_amdgcn_s_barrier();
        __builtin_amdgcn_sched_barrier(0);
        const u16* Ab = smem + (t % 3) * 12288;
        const u16* Bb = Ab + 8192;
        bf16x8 af[4], bfr[4];
#pragma unroll
        for (int mf = 0; mf < 4; ++mf)
            af[mf] = ld_frag(Ab + (wm * 64 + mf * 16 + llo) * 32 + lhi * 8);
#pragma unroll
        for (int nf = 0; nf < 4; ++nf)
            bfr[nf] = ld_frag(Bb + (wn * 64 + nf * 16 + llo) * 32 + lhi * 8);
        if (t + 2 < T) stage(t + 2, ((t + 2) % 3) * 12288);
        __builtin_amdgcn_s_setprio(1);
#pragma unroll
        for (int mf = 0; mf < 4; ++mf)
#pragma unroll
            for (int nf = 0; nf < 4; ++nf)
                acc[mf][nf] = __builtin_amdgcn_mfma_f32_16x16x32_bf16(
                    af[mf], bfr[nf], acc[mf][nf], 0, 0, 0);
        __builtin_amdgcn_s_setprio(0);
    }

    const float SC2 = 0.18033688f;  // 0.125 * log2(e)
    const int row_base = m0 + wm * 64;
    const int col_base = n0 + wn * 64;
#pragma unroll
    for (int nf = 0; nf < 4; ++nf) {
        int col = col_base + nf * 16 + llo;
        float bv = bias[col];
        const bool doScale = SCALEQ && (col < 1024);
#pragma unroll
        for (int mf = 0; mf < 4; ++mf) {
#pragma unroll
            for (int r = 0; r < 4; ++r) {
                int row = row_base + mf * 16 + lhi * 4 + r;
                float v = acc[mf][nf][r] + bv;
                if (doScale) v *= SC2;
                if (F32OUT)
                    Cf[(size_t)row * N + col] = v;
                else
                    Cb[(size_t)row * N + col] = f2bfu(v);
            }
        }
    }
}

// ---------------- GEMM B: 128x128 tile, BK=32, ring-3 (small gemm2) ------
template <int F32OUT, int SCALEQ>
__global__ __launch_bounds__(256, 3) void gemm_r4(const u16* __restrict__ A,
                                                  const u16* __restrict__ Bt,
                                                  const float* __restrict__ bias,
                                                  float* __restrict__ Cf,
                                                  u16* __restrict__ Cb,
                                                  int M, int N, int K) {
    __shared__ __align__(16) u16 smem[24576];
    const int tid = threadIdx.x;
    const int wid = tid >> 6, lane = tid & 63;
    const int llo = lane & 15, lhi = lane >> 4;
    const int wm = wid >> 1, wn = wid & 1;
    const int cpx = gridDim.x >> 3;
    const int swz = (blockIdx.x & 7) * cpx + (blockIdx.x >> 3);
    const int nb = N >> 7;
    const int m0 = (swz / nb) << 7, n0 = (swz % nb) << 7;
    const int T = K >> 5;

    f32x4 acc[4][4];
#pragma unroll
    for (int i = 0; i < 4; ++i)
#pragma unroll
        for (int j = 0; j < 4; ++j) acc[i][j] = (f32x4){0.f, 0.f, 0.f, 0.f};

    auto stage = [&](int t, int sb) {
        const int kb = t << 5;
#pragma unroll
        for (int j = 0; j < 2; ++j) {
            int c = j * 256 + tid;
            int row = c >> 2, kc = (c & 3) * 8;
            gload_lds16(A + (size_t)(m0 + row) * K + kb + kc, smem + sb + c * 8);
        }
#pragma unroll
        for (int j = 0; j < 2; ++j) {
            int c = j * 256 + tid;
            int row = c >> 2, kc = (c & 3) * 8;
            gload_lds16(Bt + (size_t)(n0 + row) * K + kb + kc,
                        smem + sb + 4096 + c * 8);
        }
    };

    stage(0, 0);
    stage(1, 8192);

    for (int t = 0; t < T; ++t) {
        if (t == T - 1)
            asm volatile("s_waitcnt vmcnt(0)" ::: "memory");
        else
            asm volatile("s_waitcnt vmcnt(4)" ::: "memory");
        __builtin_amdgcn_sched_barrier(0);
        __builtin_amdgcn_s_barrier();
        __builtin_amdgcn_sched_barrier(0);
        const u16* Ab = smem + (t % 3) * 8192;
        const u16* Bb = Ab + 4096;
        bf16x8 af[4], bfr[4];
#pragma unroll
        for (int mf = 0; mf < 4; ++mf)
            af[mf] = ld_frag(Ab + (wm * 64 + mf * 16 + llo) * 32 + lhi * 8);
#pragma unroll
        for (int nf = 0; nf < 4; ++nf)
            bfr[nf] = ld_frag(Bb + (wn * 64 + nf * 16 + llo) * 32 + lhi * 8);
        if (t + 2 < T) stage(t + 2, ((t + 2) % 3) * 8192);
        __builtin_amdgcn_s_setprio(1);
#pragma unroll
        for (int mf = 0; mf < 4; ++mf)
#pragma unroll
            for (int nf = 0; nf < 4; ++nf)
                acc[mf][nf] = __builtin_amdgcn_mfma_f32_16x16x32_bf16(
                    af[mf], bfr[nf], acc[mf][nf], 0, 0, 0);
        __builtin_amdgcn_s_setprio(0);
    }

    const float SC2 = 0.18033688f;  // 0.125 * log2(e)
    const int row_base = m0 + wm * 64;
    const int col_base = n0 + wn * 64;
#pragma unroll
    for (int nf = 0; nf < 4; ++nf) {
        int col = col_base + nf * 16 + llo;
        float bv = bias[col];
        const bool doScale = SCALEQ && (col < 1024);
#pragma unroll
        for (int mf = 0; mf < 4; ++mf) {
#pragma unroll
            for (int r = 0; r < 4; ++r) {
                int row = row_base + mf * 16 + lhi * 4 + r;
                float v = acc[mf][nf][r] + bv;
                if (doScale) v *= SC2;
                if (F32OUT)
                    Cf[(size_t)row * N + col] = v;
                else
                    Cb[(size_t)row * N + col] = f2bfu(v);
            }
        }
    }
}

// ---------------- causal flash attention (round-22 winner, restored) ----------
__global__ __launch_bounds__(512, 2) void attn_kernel(const u16* __restrict__ qkv,
                                                      u16* __restrict__ o) {
    __shared__ __align__(16) u16 smem[34048];  // K:2x8320 @0, Vt:2x8704 @16640
    const int bid = blockIdx.x;
    const int amap[8] = {7, 5, 3, 1, 6, 4, 2, 0};  // f(g+4) = f(g)-1
    const int bh = bid & 63;
    const int qc = amap[bid >> 6];
    const int b = bh >> 4, h = bh & 15;
    const int tid = threadIdx.x;
    const int wid = tid >> 6, lane = tid & 63;
    const int l31 = lane & 31, lh = lane >> 5;
    const u16* base = qkv + (size_t)b * SEQ_T * (3 * DM);
    const int qrow0 = qc * 256 + wid * 32;
    const int q_abs = qrow0 + l31;
    const int nkv2 = 2 * qc + 2;

    bf16x8 qf[4];
    {
        const u16* qp = base + (size_t)q_abs * (3 * DM) + h * HD + lh * 8;
#pragma unroll
        for (int km = 0; km < 4; ++km) qf[km] = ld_frag(qp + km * 16);
    }

    f32x16 oac0, oac1;
#pragma unroll
    for (int r = 0; r < 16; ++r) { oac0[r] = 0.f; oac1[r] = 0.f; }
    float m_run = -1e30f, l_run = 0.f;

    uint4 va, vb;
    const int vpr = tid >> 3, vm = tid & 7;

    auto stageK = [&](int kb2, int bi2) {
#pragma unroll
        for (int p = 0; p < 2; ++p) {
            int kv = p * 64 + wid * 8 + (lane >> 3);
            int cl = lane & 7;
            const u16* src = base + (size_t)(kb2 * 128 + kv) * (3 * DM) + DM + h * HD +
                             ((cl ^ (kv & 7)) * 8);
            gload_lds16(src, smem + bi2 * 8320 + (p * 8 + wid) * 520);
        }
    };
    auto loadV = [&](int kb2) {
        const u16* vp =
            base + (size_t)(kb2 * 128 + 2 * vpr) * (3 * DM) + 2 * DM + h * HD + vm * 8;
        va = *reinterpret_cast<const uint4*>(vp);
        vb = *reinterpret_cast<const uint4*>(vp + 3 * DM);
    };
    auto writeV = [&](int bi2) {
        u16 ua[8], ub[8];
        *reinterpret_cast<uint4*>(ua) = va;
        *reinterpret_cast<uint4*>(ub) = vb;
        const int cbk = vpr >> 2, off = 2 * (vpr & 3);
        const int sw = (2 * vm) & 7;
        u16* vt = smem + 16640 + bi2 * 8704;
#pragma unroll
        for (int j = 0; j < 8; ++j) {
            int d = vm * 8 + j;
            u32t val = (u32t)ua[j] | ((u32t)ub[j] << 16);
            *reinterpret_cast<u32t*>(vt + d * 136 + ((cbk ^ sw) * 8) + off) = val;
        }
    };

    loadV(0);
    stageK(0, 0);
    writeV(0);
    asm volatile("s_waitcnt lgkmcnt(0)" ::: "memory");
    asm volatile("s_waitcnt vmcnt(1)" ::: "memory");
    __builtin_amdgcn_sched_barrier(0);
    __builtin_amdgcn_s_barrier();
    __builtin_amdgcn_sched_barrier(0);

    const int vsw = (2 * (l31 >> 3)) & 7;
    const int qmax = qrow0 + 31;
    const int krow0 = (l31 >> 3) * 520 + (l31 & 7) * 64;
    const int krow1 = (4 + (l31 >> 3)) * 520 + (l31 & 7) * 64;

    for (int kb2 = 0; kb2 < nkv2; ++kb2) {
        const int cur = kb2 & 1;
        const bool pre = (kb2 + 1 < nkv2);
        if (pre) { loadV(kb2 + 1); stageK(kb2 + 1, cur ^ 1); }

#pragma unroll
        for (int s = 0; s < 2; ++s) {
            if (s == 1) {
                if (pre) asm volatile("s_waitcnt vmcnt(4)" ::: "memory");
                else     asm volatile("s_waitcnt vmcnt(0)" ::: "memory");
                __builtin_amdgcn_sched_barrier(0);
            }
            const int kv0 = kb2 * 128 + s * 64;
            if (kv0 > qmax) continue;
            f32x16 s0, s1;
#pragma unroll
            for (int r = 0; r < 16; ++r) { s0[r] = 0.f; s1[r] = 0.f; }
            const u16* kbase = smem + cur * 8320 + s * 4160;
#pragma unroll
            for (int km = 0; km < 4; ++km) {
                bf16x8 kf = ld_frag(kbase + krow0 + (((km * 2 + lh) ^ (l31 & 7)) * 8));
                s0 = __builtin_amdgcn_mfma_f32_32x32x16_bf16(kf, qf[km], s0, 0, 0, 0);
            }
#pragma unroll
            for (int km = 0; km < 4; ++km) {
                bf16x8 kf = ld_frag(kbase + krow1 + (((km * 2 + lh) ^ (l31 & 7)) * 8));
                s1 = __builtin_amdgcn_mfma_f32_32x32x16_bf16(kf, qf[km], s1, 0, 0, 0);
            }

            if (kv0 + 63 > qrow0) {
#pragma unroll
                for (int r = 0; r < 16; ++r) {
                    int ka = kv0 + (r & 3) + 8 * (r >> 2) + 4 * lh;
                    if (ka > q_abs) s0[r] = -1e30f;
                    if (ka + 32 > q_abs) s1[r] = -1e30f;
                }
            }

            float t16[16];
#pragma unroll
            for (int r = 0; r < 16; ++r) t16[r] = fmaxf(s0[r], s1[r]);
#pragma unroll
            for (int r = 0; r < 8; ++r) t16[r] = fmaxf(t16[r], t16[r + 8]);
#pragma unroll
            for (int r = 0; r < 4; ++r) t16[r] = fmaxf(t16[r], t16[r + 4]);
            float pm = fmaxf(fmaxf(t16[0], t16[1]), fmaxf(t16[2], t16[3]));
            pm = fmaxf(pm, __shfl_xor(pm, 32));
            if (!__all(pm - m_run <= 8.f)) {
                const float mnew = fmaxf(m_run, pm);
                const float sc = fexp2(m_run - mnew);
                m_run = mnew;
                l_run *= sc;
#pragma unroll
                for (int r = 0; r < 16; ++r) { oac0[r] *= sc; oac1[r] *= sc; }
            }
            float a16[16];
#pragma unroll
            for (int r = 0; r < 16; ++r) { s0[r] = fexp2(s0[r] - m_run); }
#pragma unroll
            for (int r = 0; r < 16; ++r) { s1[r] = fexp2(s1[r] - m_run); }
#pragma unroll
            for (int r = 0; r < 16; ++r) a16[r] = s0[r] + s1[r];
#pragma unroll
            for (int r = 0; r < 8; ++r) a16[r] += a16[r + 8];
#pragma unroll
            for (int r = 0; r < 4; ++r) a16[r] += a16[r + 4];
            float sum = (a16[0] + a16[1]) + (a16[2] + a16[3]);
            sum += __shfl_xor(sum, 32);
            l_run += sum;

            u32t pk0[8], pk1[8];
#pragma unroll
            for (int w = 0; w < 8; ++w) {
                float a0 = s0[2 * w], b0 = s0[2 * w + 1];
                float a1 = s1[2 * w], b1 = s1[2 * w + 1];
                asm("v_cvt_pk_bf16_f32 %0, %1, %2" : "=v"(pk0[w]) : "v"(a0), "v"(b0));
                asm("v_cvt_pk_bf16_f32 %0, %1, %2" : "=v"(pk1[w]) : "v"(a1), "v"(b1));
            }
            asm("v_permlane32_swap_b32 %0, %1" : "+v"(pk0[0]), "+v"(pk0[2]));
            asm("v_permlane32_swap_b32 %0, %1" : "+v"(pk0[1]), "+v"(pk0[3]));
            asm("v_permlane32_swap_b32 %0, %1" : "+v"(pk0[4]), "+v"(pk0[6]));
            asm("v_permlane32_swap_b32 %0, %1" : "+v"(pk0[5]), "+v"(pk0[7]));
            asm("v_permlane32_swap_b32 %0, %1" : "+v"(pk1[0]), "+v"(pk1[2]));
            asm("v_permlane32_swap_b32 %0, %1" : "+v"(pk1[1]), "+v"(pk1[3]));
            asm("v_permlane32_swap_b32 %0, %1" : "+v"(pk1[4]), "+v"(pk1[6]));
            asm("v_permlane32_swap_b32 %0, %1" : "+v"(pk1[5]), "+v"(pk1[7]));
            bf16x8 pf[4];
            {
                uint4 t0 = {pk0[0], pk0[1], pk0[2], pk0[3]};
                uint4 t1 = {pk0[4], pk0[5], pk0[6], pk0[7]};
                uint4 t2 = {pk1[0], pk1[1], pk1[2], pk1[3]};
                uint4 t3 = {pk1[4], pk1[5], pk1[6], pk1[7]};
                pf[0] = __builtin_bit_cast(bf16x8, t0);
                pf[1] = __builtin_bit_cast(bf16x8, t1);
                pf[2] = __builtin_bit_cast(bf16x8, t2);
                pf[3] = __builtin_bit_cast(bf16x8, t3);
            }

            const u16* vbase = smem + 16640 + cur * 8704;
#pragma unroll
            for (int km = 0; km < 4; ++km) {
                bf16x8 vf = ld_frag(vbase + l31 * 136 +
                                    ((s * 8 + ((km * 2 + lh) ^ vsw)) * 8));
                oac0 = __builtin_amdgcn_mfma_f32_32x32x16_bf16(vf, pf[km], oac0, 0, 0, 0);
            }
#pragma unroll
            for (int km = 0; km < 4; ++km) {
                bf16x8 vf = ld_frag(vbase + (32 + l31) * 136 +
                                    ((s * 8 + ((km * 2 + lh) ^ vsw)) * 8));
                oac1 = __builtin_amdgcn_mfma_f32_32x32x16_bf16(vf, pf[km], oac1, 0, 0, 0);
            }
        }

        if (pre) {
            writeV(cur ^ 1);
            asm volatile("s_waitcnt lgkmcnt(0)" ::: "memory");
            asm volatile("s_waitcnt vmcnt(1)" ::: "memory");
        } else {
            asm volatile("s_waitcnt lgkmcnt(0)" ::: "memory");
        }
        __builtin_amdgcn_sched_barrier(0);
        __builtin_amdgcn_s_barrier();
        __builtin_amdgcn_sched_barrier(0);
    }

    const float inv = 1.f / l_run;
    u16* osh = smem + wid * 2240;
#pragma unroll
    for (int r = 0; r < 16; ++r) {
        int dl = (r & 3) + 8 * (r >> 2) + 4 * lh;
        osh[l31 * 70 + dl] = f2bfu(oac0[r] * inv);
        osh[l31 * 70 + 32 + dl] = f2bfu(oac1[r] * inv);
    }
    __syncthreads();
    {
        const u16* rs = osh + l31 * 70 + lh * 32;
        u16* op = o + (size_t)(b * SEQ_T + qrow0 + l31) * DM + h * HD + lh * 32;
        u32t w[16];
#pragma unroll
        for (int i = 0; i < 16; ++i) w[i] = *reinterpret_cast<const u32t*>(rs + i * 2);
#pragma unroll
        for (int i = 0; i < 4; ++i) {
            uint4 t = {w[4 * i], w[4 * i + 1], w[4 * i + 2], w[4 * i + 3]};
            *reinterpret_cast<uint4*>(op + 8 * i) = t;
        }
    }
}

extern "C" void kernel_launch(void* const* d_in, const int* in_sizes, int n_in,
                              void* d_out, int out_size, void* d_ws, size_t ws_size,
                              hipStream_t stream) {
    const float* x = (const float*)d_in[0];
    const float* Wqkv = (const float*)d_in[1];
    const float* bqkv = (const float*)d_in[2];
    const float* Wproj = (const float*)d_in[3];
    const float* bproj = (const float*)d_in[4];
    float* out = (float*)d_out;
    char* ws = (char*)d_ws;

    u16* xb   = (u16*)(ws);                         // 16,777,216 B
    u16* wtq  = (u16*)(ws + 16777216);              //  6,291,456 B
    u16* wtp  = (u16*)(ws + 23068672);              //  2,097,152 B
    u16* qkvb = (u16*)(ws + 25165824);              // 50,331,648 B
    u16* ob   = (u16*)(ws + 75497472);              // 16,777,216 B

    prep_kernel<<<5120, 256, 0, stream>>>(x, xb, Wqkv, wtq, Wproj, wtp);

    gemm_r3<0, 1><<<768, 512, 0, stream>>>(
        xb, wtq, bqkv, nullptr, qkvb, 8192, 3072, 1024);

    attn_kernel<<<512, 512, 0, stream>>>(qkvb, ob);

    gemm_r4<1, 0><<<512, 256, 0, stream>>>(
        ob, wtp, bproj, out, nullptr, 8192, 1024, 1024);
}